// Round 10
// baseline (297.009 us; speedup 1.0000x reference)
//
#include <hip/hip_runtime.h>
#include <hip/hip_bf16.h>

using bf16 = __hip_bfloat16;
typedef __bf16 bf16x8 __attribute__((ext_vector_type(8)));
typedef __bf16 bf16x4 __attribute__((ext_vector_type(4)));
typedef float f32x4 __attribute__((ext_vector_type(4)));

#define BK 64

// ---------------------------------------------------------------------------
// Staging helper: 16B per lane via global_load_lds, wave-uniform LDS base.
// ---------------------------------------------------------------------------
__device__ __forceinline__ void stage16(const bf16* gsrc, bf16* lds_base)
{
    __builtin_amdgcn_global_load_lds(
        (__attribute__((address_space(1))) void*)(void*)gsrc,
        (__attribute__((address_space(3))) void*)(void*)lds_base,
        16, 0, 0);
}

// LDS chunk swizzle: slot (row, c) holds global chunk (row, c^(row&7)).
// Kills the 16-way ds_read_b128 bank conflict (1.65e7 -> 0, measured R5).
// R8 lesson: 256x128 fc1 tile regressed (occupancy 28->16%); 128^2 is the
// sweet spot. R9 lesson: 1-block/CU kernels (t2_direct) are latency chains.

// Register-staged fp32 delta segment: load 8 fp32, scale by gw, pack bf16,
// ds_write_b128 into the swizzled slot (per-lane scatter is fine for
// ds_write; only global_load_lds needs the wave-uniform base).
__device__ __forceinline__ void stage_f32_gw(const float* __restrict__ acc128,
                                             const float* __restrict__ gw,
                                             int grow, int ksr, int cb,
                                             bf16* lds_slot)
{
    const float* src = acc128 + (size_t)grow * 128 + ksr + cb * 8;
    const float* g   = gw + (grow >> 9) * 128 + ksr + cb * 8;
    const float4 v0 = *(const float4*)src;
    const float4 v1 = *(const float4*)(src + 4);
    const float4 g0 = *(const float4*)g;
    const float4 g1 = *(const float4*)(g + 4);
    bf16x8 o;
    o[0] = (__bf16)(v0.x * g0.x); o[1] = (__bf16)(v0.y * g0.y);
    o[2] = (__bf16)(v0.z * g0.z); o[3] = (__bf16)(v0.w * g0.w);
    o[4] = (__bf16)(v1.x * g1.x); o[5] = (__bf16)(v1.y * g1.y);
    o[6] = (__bf16)(v1.z * g1.z); o[7] = (__bf16)(v1.w * g1.w);
    *(bf16x8*)lds_slot = o;
}

// ---------------------------------------------------------------------------
// fc1: 128x128 tiled MFMA GEMM. C = relu([A0 | A1*gw] @ [B0;B1]^T + bias).
// A0 bf16 [M,K0]; A1 fp32 [M,128] scaled inline by gw[16,128] (delta seg).
// ---------------------------------------------------------------------------
__global__ __launch_bounds__(256)
void gemm_bt(const bf16* __restrict__ A0, int lda0, int K0,
             const float* __restrict__ A1, const float* __restrict__ gw,
             const bf16* __restrict__ B0, int ldb0,
             const bf16* __restrict__ B1, int ldb1,
             const float* __restrict__ bias,
             int relu,
             bf16* __restrict__ C, int ldc)
{
    __shared__ bf16 sA[128 * BK];
    __shared__ bf16 sB[128 * BK];

    const int t = threadIdx.x;
    const int w = t >> 6;
    const int l = t & 63;
    const int wm = w >> 1;
    const int wn = w & 1;
    const int r = l & 15;
    const int q = l >> 4;
    const int sw = r & 7;
    const int rowA0 = blockIdx.x * 128;
    const int rowB0 = blockIdx.y * 128;

    f32x4 acc[4][4];
#pragma unroll
    for (int i = 0; i < 4; ++i)
#pragma unroll
        for (int j = 0; j < 4; ++j)
            acc[i][j] = (f32x4){0.f, 0.f, 0.f, 0.f};

    const int nK = (K0 + 128) >> 6;
    for (int kt = 0; kt < nK; ++kt) {
        const int k0 = kt << 6;

        __syncthreads();
        if (k0 < K0) {
#pragma unroll
            for (int it = 0; it < 4; ++it) {
                const int L   = it * 256 + t;
                const int row = L >> 3;
                const int cb  = (L & 7) ^ (row & 7);
                stage16(A0 + (size_t)(rowA0 + row) * lda0 + k0 + cb * 8,
                        sA + (size_t)(it * 256 + (w << 6)) * 8);
                stage16(B0 + (size_t)(rowB0 + row) * ldb0 + k0 + cb * 8,
                        sB + (size_t)(it * 256 + (w << 6)) * 8);
            }
        } else {
            const int ksr = k0 - K0;   // 0 or 64
#pragma unroll
            for (int it = 0; it < 4; ++it) {
                const int L   = it * 256 + t;
                const int row = L >> 3;
                const int cb  = (L & 7) ^ (row & 7);
                stage_f32_gw(A1, gw, rowA0 + row, ksr, cb, &sA[(size_t)L * 8]);
                stage16(B1 + (size_t)(rowB0 + row) * ldb1 + ksr + cb * 8,
                        sB + (size_t)(it * 256 + (w << 6)) * 8);
            }
        }
        __syncthreads();

#pragma unroll
        for (int kk = 0; kk < 2; ++kk) {
            const int ch = ((kk * 4 + q) ^ sw) * 8;
            bf16x8 aF[4], bF[4];
#pragma unroll
            for (int i = 0; i < 4; ++i)
                aF[i] = *(const bf16x8*)&sA[(wm * 64 + i * 16 + r) * BK + ch];
#pragma unroll
            for (int j = 0; j < 4; ++j)
                bF[j] = *(const bf16x8*)&sB[(wn * 64 + j * 16 + r) * BK + ch];
#pragma unroll
            for (int i = 0; i < 4; ++i)
#pragma unroll
                for (int j = 0; j < 4; ++j)
                    acc[i][j] = __builtin_amdgcn_mfma_f32_16x16x32_bf16(
                        aF[i], bF[j], acc[i][j], 0, 0, 0);
        }
    }

    // C/D layout: col = lane&15, row = quad*4 + reg (m89/m91 verified)
#pragma unroll
    for (int i = 0; i < 4; ++i)
#pragma unroll
        for (int j = 0; j < 4; ++j)
#pragma unroll
            for (int rr = 0; rr < 4; ++rr) {
                const int row = rowA0 + wm * 64 + i * 16 + q * 4 + rr;
                const int col = rowB0 + wn * 64 + j * 16 + r;
                float v = acc[i][j][rr];
                if (bias) v += bias[col];
                if (relu) v = v > 0.f ? v : 0.f;
                C[(size_t)row * ldc + col] = __float2bfloat16(v);
            }
}

// ---------------------------------------------------------------------------
// fc2: 64x128 tile. out(fp32) = [A0 | A1*gw] @ [B0;B1]^T + bias.
// ---------------------------------------------------------------------------
__global__ __launch_bounds__(256)
void gemm_bt64(const bf16* __restrict__ A0, int lda0, int K0,
               const float* __restrict__ A1, const float* __restrict__ gw,
               const bf16* __restrict__ B0, int ldb0,
               const bf16* __restrict__ B1, int ldb1,
               const float* __restrict__ bias,
               float* __restrict__ Cf, int ldc)
{
    __shared__ bf16 sA[64 * BK];
    __shared__ bf16 sB[128 * BK];

    const int t = threadIdx.x;
    const int w = t >> 6;
    const int l = t & 63;
    const int wn = w;
    const int r = l & 15;
    const int q = l >> 4;
    const int sw = r & 7;
    const int rowA0 = blockIdx.x * 64;
    const int rowB0 = blockIdx.y * 128;

    f32x4 acc[4][2];
#pragma unroll
    for (int i = 0; i < 4; ++i)
#pragma unroll
        for (int j = 0; j < 2; ++j)
            acc[i][j] = (f32x4){0.f, 0.f, 0.f, 0.f};

    const int nK = (K0 + 128) >> 6;
    for (int kt = 0; kt < nK; ++kt) {
        const int k0 = kt << 6;

        __syncthreads();
        if (k0 < K0) {
#pragma unroll
            for (int it = 0; it < 2; ++it) {
                const int L   = it * 256 + t;
                const int row = L >> 3;
                const int cb  = (L & 7) ^ (row & 7);
                stage16(A0 + (size_t)(rowA0 + row) * lda0 + k0 + cb * 8,
                        sA + (size_t)(it * 256 + (w << 6)) * 8);
            }
#pragma unroll
            for (int it = 0; it < 4; ++it) {
                const int L   = it * 256 + t;
                const int row = L >> 3;
                const int cb  = (L & 7) ^ (row & 7);
                stage16(B0 + (size_t)(rowB0 + row) * ldb0 + k0 + cb * 8,
                        sB + (size_t)(it * 256 + (w << 6)) * 8);
            }
        } else {
            const int ksr = k0 - K0;
#pragma unroll
            for (int it = 0; it < 2; ++it) {
                const int L   = it * 256 + t;
                const int row = L >> 3;
                const int cb  = (L & 7) ^ (row & 7);
                stage_f32_gw(A1, gw, rowA0 + row, ksr, cb, &sA[(size_t)L * 8]);
            }
#pragma unroll
            for (int it = 0; it < 4; ++it) {
                const int L   = it * 256 + t;
                const int row = L >> 3;
                const int cb  = (L & 7) ^ (row & 7);
                stage16(B1 + (size_t)(rowB0 + row) * ldb1 + ksr + cb * 8,
                        sB + (size_t)(it * 256 + (w << 6)) * 8);
            }
        }
        __syncthreads();

#pragma unroll
        for (int kk = 0; kk < 2; ++kk) {
            const int ch = ((kk * 4 + q) ^ sw) * 8;
            bf16x8 aF[4], bF[2];
#pragma unroll
            for (int i = 0; i < 4; ++i)
                aF[i] = *(const bf16x8*)&sA[(i * 16 + r) * BK + ch];
#pragma unroll
            for (int j = 0; j < 2; ++j)
                bF[j] = *(const bf16x8*)&sB[(wn * 32 + j * 16 + r) * BK + ch];
#pragma unroll
            for (int i = 0; i < 4; ++i)
#pragma unroll
                for (int j = 0; j < 2; ++j)
                    acc[i][j] = __builtin_amdgcn_mfma_f32_16x16x32_bf16(
                        aF[i], bF[j], acc[i][j], 0, 0, 0);
        }
    }

#pragma unroll
    for (int i = 0; i < 4; ++i)
#pragma unroll
        for (int j = 0; j < 2; ++j)
#pragma unroll
            for (int rr = 0; rr < 4; ++rr) {
                const int row = rowA0 + i * 16 + q * 4 + rr;
                const int col = rowB0 + wn * 32 + j * 16 + r;
                Cf[(size_t)row * ldc + col] = acc[i][j][rr] + bias[col];
            }
}

// ---------------------------------------------------------------------------
// Fused router + t1 GEMM, 64-row tiles (384 blocks for TLP).
// B = [gate_w1 ; SVH1] contiguous [384,768]. Grid (128, 3), K=768 full.
//   y=0,1 (router): bias+relu+64-row sum -> atomicAdd gsum[16,256].
//   y=2   (t1):     raw fp32 x@SVH1^T -> t1acc (non-atomic).
// ---------------------------------------------------------------------------
__global__ __launch_bounds__(256)
void rt1_kernel(const bf16* __restrict__ A, int lda,
                const bf16* __restrict__ B, int ldb,
                const float* __restrict__ gate_b1,
                float* __restrict__ gsum, float* __restrict__ t1acc)
{
    __shared__ bf16 sA[64 * BK];
    __shared__ bf16 sB[128 * BK];

    const int t = threadIdx.x;
    const int w = t >> 6;
    const int l = t & 63;
    const int wn = w;
    const int r = l & 15;
    const int q = l >> 4;
    const int sw = r & 7;
    const int rowA0 = blockIdx.x * 64;
    const int rowB0 = blockIdx.y * 128;
    const int b = rowA0 >> 9;

    f32x4 acc[4][2];
#pragma unroll
    for (int i = 0; i < 4; ++i)
#pragma unroll
        for (int j = 0; j < 2; ++j)
            acc[i][j] = (f32x4){0.f, 0.f, 0.f, 0.f};

    for (int kt = 0; kt < 12; ++kt) {      // K = 768
        const int ks = kt << 6;

        __syncthreads();
#pragma unroll
        for (int it = 0; it < 2; ++it) {
            const int L   = it * 256 + t;
            const int row = L >> 3;
            const int cb  = (L & 7) ^ (row & 7);
            stage16(A + (size_t)(rowA0 + row) * lda + ks + cb * 8,
                    sA + (size_t)(it * 256 + (w << 6)) * 8);
        }
#pragma unroll
        for (int it = 0; it < 4; ++it) {
            const int L   = it * 256 + t;
            const int row = L >> 3;
            const int cb  = (L & 7) ^ (row & 7);
            stage16(B + (size_t)(rowB0 + row) * ldb + ks + cb * 8,
                    sB + (size_t)(it * 256 + (w << 6)) * 8);
        }
        __syncthreads();

#pragma unroll
        for (int kk = 0; kk < 2; ++kk) {
            const int ch = ((kk * 4 + q) ^ sw) * 8;
            bf16x8 aF[4], bF[2];
#pragma unroll
            for (int i = 0; i < 4; ++i)
                aF[i] = *(const bf16x8*)&sA[(i * 16 + r) * BK + ch];
#pragma unroll
            for (int j = 0; j < 2; ++j)
                bF[j] = *(const bf16x8*)&sB[(wn * 32 + j * 16 + r) * BK + ch];
#pragma unroll
            for (int i = 0; i < 4; ++i)
#pragma unroll
                for (int j = 0; j < 2; ++j)
                    acc[i][j] = __builtin_amdgcn_mfma_f32_16x16x32_bf16(
                        aF[i], bF[j], acc[i][j], 0, 0, 0);
        }
    }

    if (rowB0 < 256) {
#pragma unroll
        for (int j = 0; j < 2; ++j) {
            const int col = rowB0 + wn * 32 + j * 16 + r;
            const float bc = gate_b1[col];
            float s = 0.f;
#pragma unroll
            for (int i = 0; i < 4; ++i)
#pragma unroll
                for (int rr = 0; rr < 4; ++rr) {
                    const float v = acc[i][j][rr] + bc;
                    s += v > 0.f ? v : 0.f;
                }
            s += __shfl_xor(s, 16, 64);
            s += __shfl_xor(s, 32, 64);
            if (q == 0) atomicAdd(&gsum[b * 256 + col], s);
        }
    } else {
#pragma unroll
        for (int i = 0; i < 4; ++i)
#pragma unroll
            for (int j = 0; j < 2; ++j)
#pragma unroll
                for (int rr = 0; rr < 4; ++rr) {
                    const int row = rowA0 + i * 16 + q * 4 + rr;
                    const int col = wn * 32 + j * 16 + r;
                    t1acc[(size_t)row * 128 + col] = acc[i][j][rr];
                }
    }
}

// ---------------------------------------------------------------------------
// t2 split-K: grid (128, 1, 8), 64x128 tiles, 6 K-tiles per z, atomicAdd
// into pre-zeroed t2acc fp32. 1024 blocks = 4/CU for latency hiding.
// ---------------------------------------------------------------------------
__global__ __launch_bounds__(256)
void t2_splitk(const bf16* __restrict__ A, int lda,
               const bf16* __restrict__ B, int ldb,
               float* __restrict__ Cacc)
{
    __shared__ bf16 sA[64 * BK];
    __shared__ bf16 sB[128 * BK];

    const int t = threadIdx.x;
    const int w = t >> 6;
    const int l = t & 63;
    const int wn = w;
    const int r = l & 15;
    const int q = l >> 4;
    const int sw = r & 7;
    const int rowA0 = blockIdx.x * 64;
    const int ksbase = blockIdx.z * 6 * BK;

    f32x4 acc[4][2];
#pragma unroll
    for (int i = 0; i < 4; ++i)
#pragma unroll
        for (int j = 0; j < 2; ++j)
            acc[i][j] = (f32x4){0.f, 0.f, 0.f, 0.f};

    for (int kt = 0; kt < 6; ++kt) {
        const int ks = ksbase + kt * BK;

        __syncthreads();
#pragma unroll
        for (int it = 0; it < 2; ++it) {
            const int L   = it * 256 + t;
            const int row = L >> 3;
            const int cb  = (L & 7) ^ (row & 7);
            stage16(A + (size_t)(rowA0 + row) * lda + ks + cb * 8,
                    sA + (size_t)(it * 256 + (w << 6)) * 8);
        }
#pragma unroll
        for (int it = 0; it < 4; ++it) {
            const int L   = it * 256 + t;
            const int row = L >> 3;
            const int cb  = (L & 7) ^ (row & 7);
            stage16(B + (size_t)row * ldb + ks + cb * 8,
                    sB + (size_t)(it * 256 + (w << 6)) * 8);
        }
        __syncthreads();

#pragma unroll
        for (int kk = 0; kk < 2; ++kk) {
            const int ch = ((kk * 4 + q) ^ sw) * 8;
            bf16x8 aF[4], bF[2];
#pragma unroll
            for (int i = 0; i < 4; ++i)
                aF[i] = *(const bf16x8*)&sA[(i * 16 + r) * BK + ch];
#pragma unroll
            for (int j = 0; j < 2; ++j)
                bF[j] = *(const bf16x8*)&sB[(wn * 32 + j * 16 + r) * BK + ch];
#pragma unroll
            for (int i = 0; i < 4; ++i)
#pragma unroll
                for (int j = 0; j < 2; ++j)
                    acc[i][j] = __builtin_amdgcn_mfma_f32_16x16x32_bf16(
                        aF[i], bF[j], acc[i][j], 0, 0, 0);
        }
    }

#pragma unroll
    for (int i = 0; i < 4; ++i)
#pragma unroll
        for (int j = 0; j < 2; ++j)
#pragma unroll
            for (int rr = 0; rr < 4; ++rr) {
                const int row = rowA0 + i * 16 + q * 4 + rr;
                const int col = wn * 32 + j * 16 + r;
                atomicAdd(&Cacc[(size_t)row * 128 + col], acc[i][j][rr]);
            }
}

// ---------------------------------------------------------------------------
// Fused prep: fp32->bf16 casts + coalesced LDS-tile U transposes + merged
// biases + zeroing of gsum and t2acc. One launch.
// ---------------------------------------------------------------------------
__device__ __forceinline__ void cvt_range(const float* src, bf16* dst, int base, int t)
{
    const int i = base * 256 + t;
    const float4 v = ((const float4*)src)[i];
    ((bf16x4*)dst)[i] = (bf16x4){(__bf16)v.x, (__bf16)v.y, (__bf16)v.z, (__bf16)v.w};
}

__device__ __forceinline__ void transpose_tile(const float* U, bf16* UT, int F,
                                               int bx, int by, int t,
                                               float (*sh)[65])
{
    const int f0 = bx * 64, ek0 = by * 64;
#pragma unroll
    for (int i = 0; i < 16; ++i) {
        const int row = i * 4 + (t >> 6);
        const int col = t & 63;
        sh[row][col] = U[(size_t)(ek0 + row) * F + f0 + col];
    }
    __syncthreads();
#pragma unroll
    for (int i = 0; i < 16; ++i) {
        const int row = i * 4 + (t >> 6);
        const int col = t & 63;
        UT[(size_t)(f0 + row) * 128 + ek0 + col] = __float2bfloat16(sh[col][row]);
    }
}

__global__ void prep_all(const float* __restrict__ x,    bf16* __restrict__ xb,
                         const float* __restrict__ W1,   bf16* __restrict__ W1b,
                         const float* __restrict__ W2,   bf16* __restrict__ W2b,
                         const float* __restrict__ gw1,  bf16* __restrict__ gw1b,
                         const float* __restrict__ gw2,  bf16* __restrict__ gw2b,
                         const float* __restrict__ SVH1, bf16* __restrict__ svh1b,
                         const float* __restrict__ SVH2, bf16* __restrict__ svh2b,
                         const float* __restrict__ U1,   bf16* __restrict__ U1T,
                         const float* __restrict__ U2,   bf16* __restrict__ U2T,
                         const float* __restrict__ b1,   const float* __restrict__ TB1,
                         const float* __restrict__ b2,   const float* __restrict__ TB2,
                         float* __restrict__ b1m, float* __restrict__ b2m,
                         float* __restrict__ gsum, float* __restrict__ t2acc)
{
    __shared__ float sh[64][65];
    const int b = blockIdx.x;
    const int t = threadIdx.x;
    if      (b < 6144)  cvt_range(x,   xb,   b,         t);
    else if (b < 8448)  cvt_range(W1,  W1b,  b - 6144,  t);
    else if (b < 10752) cvt_range(W2,  W2b,  b - 8448,  t);
    else if (b < 10944) cvt_range(gw1, gw1b, b - 10752, t);
    else if (b < 10976) cvt_range(gw2, gw2b, b - 10944, t);
    else if (b < 11072) cvt_range(SVH1, svh1b, b - 10976, t);
    else if (b < 11456) cvt_range(SVH2, svh2b, b - 11072, t);
    else if (b < 11552) {          // U1 [128,3072] -> U1T: 48 x 2 tiles
        const int b2 = b - 11456;
        transpose_tile(U1, U1T, 3072, b2 >> 1, b2 & 1, t, sh);
    } else if (b < 11576) {        // U2 [128,768] -> U2T: 12 x 2 tiles
        const int b2 = b - 11552;
        transpose_tile(U2, U2T, 768, b2 >> 1, b2 & 1, t, sh);
    } else if (b < 11591) {        // merged biases
        const int i = (b - 11576) * 256 + t;
        if (i < 3072) {
            float s = 0.f;
            for (int e = 0; e < 8; ++e) s += TB1[e * 3072 + i];
            b1m[i] = b1[i] + 0.2f * s;
        } else if (i < 3840) {
            const int j = i - 3072;
            float s = 0.f;
            for (int e = 0; e < 8; ++e) s += TB2[e * 768 + j];
            b2m[j] = b2[j] + 0.2f * s;
        }
    } else if (b < 11607) {        // zero gsum[4096]
        const int i = (b - 11591) * 256 + t;
        gsum[i] = 0.f;
    } else {                       // zero t2acc: 1M floats as float4
        const int i = (b - 11607) * 256 + t;
        ((float4*)t2acc)[i] = (float4){0.f, 0.f, 0.f, 0.f};
    }
}

// gw[b,c] = gate_b2[c] + (1/512) * sum_j gsum[b,j] * gate_w2[c,j]
__global__ void gw_kernel(const float* __restrict__ gsum, const bf16* __restrict__ gw2b,
                          const float* __restrict__ gate_b2, float* __restrict__ gw)
{
    const int b = blockIdx.x;
    const int c = threadIdx.x;
    float s = 0.f;
    for (int j = 0; j < 256; ++j)
        s += gsum[b * 256 + j] * __bfloat162float(gw2b[c * 256 + j]);
    gw[b * 128 + c] = gate_b2[c] + s * (1.0f / 512.0f);
}

// ---------------------------------------------------------------------------
extern "C" void kernel_launch(void* const* d_in, const int* in_sizes, int n_in,
                              void* d_out, int out_size, void* d_ws, size_t ws_size,
                              hipStream_t stream)
{
    const float* x       = (const float*)d_in[0];
    const float* gate_w1 = (const float*)d_in[1];
    const float* gate_b1 = (const float*)d_in[2];
    const float* gate_w2 = (const float*)d_in[3];
    const float* gate_b2 = (const float*)d_in[4];
    const float* W1      = (const float*)d_in[5];
    const float* b1      = (const float*)d_in[6];
    const float* W2      = (const float*)d_in[7];
    const float* b2      = (const float*)d_in[8];
    const float* U1      = (const float*)d_in[9];
    const float* SVH1    = (const float*)d_in[10];
    const float* U2      = (const float*)d_in[11];
    const float* SVH2    = (const float*)d_in[12];
    const float* TB1     = (const float*)d_in[13];
    const float* TB2     = (const float*)d_in[14];
    float* out = (float*)d_out;                     // [8192, 768] fp32

    char* p = (char*)d_ws;
    auto alloc = [&](size_t bytes) {
        char* q = p;
        p += (bytes + 255) & ~(size_t)255;
        return q;
    };
    bf16* hbuf  = (bf16*)alloc((size_t)8192 * 3072 * 2);
    bf16* xb    = (bf16*)alloc((size_t)8192 * 768 * 2);
    bf16* W1b   = (bf16*)alloc((size_t)3072 * 768 * 2);
    bf16* W2b   = (bf16*)alloc((size_t)768 * 3072 * 2);
    // gw1b and svh1b MUST be contiguous: rt1_kernel treats them as one
    // [384, 768] B matrix. 256*768*2 = 393216 B (multiple of 256 -> no pad).
    bf16* gw1b  = (bf16*)alloc((size_t)256 * 768 * 2);
    bf16* svh1b = (bf16*)alloc((size_t)128 * 768 * 2);
    bf16* gw2b  = (bf16*)alloc((size_t)128 * 256 * 2);
    bf16* svh2b = (bf16*)alloc((size_t)128 * 3072 * 2);
    bf16* U1T   = (bf16*)alloc((size_t)3072 * 128 * 2);
    bf16* U2T   = (bf16*)alloc((size_t)768 * 128 * 2);
    float* gsum = (float*)alloc(16 * 256 * 4);
    float* gw   = (float*)alloc(2048 * 4);
    float* b1m  = (float*)alloc(3072 * 4);
    float* b2m  = (float*)alloc(768 * 4);
    float* t1acc = (float*)alloc((size_t)8192 * 128 * 4);
    float* t2acc = (float*)alloc((size_t)8192 * 128 * 4);

    const dim3 blk(256);

    prep_all<<<12631, blk, 0, stream>>>(x, xb, W1, W1b, W2, W2b,
                                        gate_w1, gw1b, gate_w2, gw2b,
                                        SVH1, svh1b, SVH2, svh2b,
                                        U1, U1T, U2, U2T,
                                        b1, TB1, b2, TB2, b1m, b2m,
                                        gsum, t2acc);

    // fused router + t1raw (64-row tiles, 384 blocks)
    rt1_kernel<<<dim3(128, 3), blk, 0, stream>>>(xb, 768, gw1b, 768,
                                                 gate_b1, gsum, t1acc);
    // gw = gsum/512 @ gate_w2^T + gate_b2              [16, 128]
    gw_kernel<<<16, 128, 0, stream>>>(gsum, gw2b, gate_b2, gw);

    // h = relu([x | t1acc*gw] @ [W1|U1T]^T + b1m)      [8192, 3072]
    gemm_bt<<<dim3(64, 24), blk, 0, stream>>>(xb, 768, 768, t1acc, gw,
                                              W1b, 768, U1T, 128,
                                              b1m, 1, hbuf, 3072);

    // t2acc += h @ SVH2^T  (split-K z=8, 1024 blocks)  [8192, 128]
    t2_splitk<<<dim3(128, 1, 8), blk, 0, stream>>>(hbuf, 3072, svh2b, 3072, t2acc);

    // out = [h | t2acc*gw] @ [W2|U2T]^T + b2m  (fp32)  [8192, 768]
    gemm_bt64<<<dim3(128, 6), blk, 0, stream>>>(hbuf, 3072, 3072, t2acc, gw,
                                                W2b, 3072, U2T, 128,
                                                b2m, out, 768);
}

// Round 11
// 281.571 us; speedup vs baseline: 1.0548x; 1.0548x over previous
//
#include <hip/hip_runtime.h>
#include <hip/hip_bf16.h>

using bf16 = __hip_bfloat16;
typedef __bf16 bf16x8 __attribute__((ext_vector_type(8)));
typedef __bf16 bf16x4 __attribute__((ext_vector_type(4)));
typedef float f32x4 __attribute__((ext_vector_type(4)));

#define BK 64

// ---------------------------------------------------------------------------
// Staging helper: 16B per lane via global_load_lds, wave-uniform LDS base.
// ---------------------------------------------------------------------------
__device__ __forceinline__ void stage16(const bf16* gsrc, bf16* lds_base)
{
    __builtin_amdgcn_global_load_lds(
        (__attribute__((address_space(1))) void*)(void*)gsrc,
        (__attribute__((address_space(3))) void*)(void*)lds_base,
        16, 0, 0);
}

// LDS chunk swizzle: slot (row, c) holds global chunk (row, c^(row&7)).
// Kills the 16-way ds_read_b128 bank conflict (1.65e7 -> 0, measured R5).
// R8: 256x128 fc1 tile regressed (occupancy 28->16%); 128^2 is the sweet
// spot. R9: 1-block/CU kernels are latency chains. R10: inline fp32*gw
// staging in the GEMM K-loop regressed fc1 67->89 (VGPR 72->104, blocking
// loads) — keep GEMM staging all-bf16 global_load_lds, scale in a tiny
// separate pass.

// ---------------------------------------------------------------------------
// fc1: 128x128 tiled MFMA GEMM. C = relu([A0|A1] @ [B0;B1]^T + bias), bf16.
// Two K-segments (dense | rank-128 delta). Block=256 (4 waves, 2x2).
// ---------------------------------------------------------------------------
__global__ __launch_bounds__(256)
void gemm_bt(const bf16* __restrict__ A0, int lda0, int K0,
             const bf16* __restrict__ A1, int lda1, int K1,
             const bf16* __restrict__ B0, int ldb0,
             const bf16* __restrict__ B1, int ldb1,
             const float* __restrict__ bias,
             int relu,
             bf16* __restrict__ C, int ldc)
{
    __shared__ bf16 sA[128 * BK];
    __shared__ bf16 sB[128 * BK];

    const int t = threadIdx.x;
    const int w = t >> 6;
    const int l = t & 63;
    const int wm = w >> 1;
    const int wn = w & 1;
    const int r = l & 15;
    const int q = l >> 4;
    const int sw = r & 7;
    const int rowA0 = blockIdx.x * 128;
    const int rowB0 = blockIdx.y * 128;

    f32x4 acc[4][4];
#pragma unroll
    for (int i = 0; i < 4; ++i)
#pragma unroll
        for (int j = 0; j < 4; ++j)
            acc[i][j] = (f32x4){0.f, 0.f, 0.f, 0.f};

    const int nK = (K0 + K1) >> 6;
    for (int kt = 0; kt < nK; ++kt) {
        const int k0 = kt << 6;
        const bf16 *Ap, *Bp;
        int la, lb, ks;
        if (k0 < K0) { Ap = A0; la = lda0; Bp = B0; lb = ldb0; ks = k0; }
        else         { Ap = A1; la = lda1; Bp = B1; lb = ldb1; ks = k0 - K0; }

        __syncthreads();
#pragma unroll
        for (int it = 0; it < 4; ++it) {
            const int L   = it * 256 + t;
            const int row = L >> 3;
            const int cb  = (L & 7) ^ (row & 7);   // swizzled source chunk
            stage16(Ap + (size_t)(rowA0 + row) * la + ks + cb * 8,
                    sA + (size_t)(it * 256 + (w << 6)) * 8);
            stage16(Bp + (size_t)(rowB0 + row) * lb + ks + cb * 8,
                    sB + (size_t)(it * 256 + (w << 6)) * 8);
        }
        __syncthreads();

#pragma unroll
        for (int kk = 0; kk < 2; ++kk) {
            const int ch = ((kk * 4 + q) ^ sw) * 8;
            bf16x8 aF[4], bF[4];
#pragma unroll
            for (int i = 0; i < 4; ++i)
                aF[i] = *(const bf16x8*)&sA[(wm * 64 + i * 16 + r) * BK + ch];
#pragma unroll
            for (int j = 0; j < 4; ++j)
                bF[j] = *(const bf16x8*)&sB[(wn * 64 + j * 16 + r) * BK + ch];
#pragma unroll
            for (int i = 0; i < 4; ++i)
#pragma unroll
                for (int j = 0; j < 4; ++j)
                    acc[i][j] = __builtin_amdgcn_mfma_f32_16x16x32_bf16(
                        aF[i], bF[j], acc[i][j], 0, 0, 0);
        }
    }

    // C/D layout: col = lane&15, row = quad*4 + reg (m89/m91 verified)
#pragma unroll
    for (int i = 0; i < 4; ++i)
#pragma unroll
        for (int j = 0; j < 4; ++j)
#pragma unroll
            for (int rr = 0; rr < 4; ++rr) {
                const int row = rowA0 + wm * 64 + i * 16 + q * 4 + rr;
                const int col = rowB0 + wn * 64 + j * 16 + r;
                float v = acc[i][j][rr];
                if (bias) v += bias[col];
                if (relu) v = v > 0.f ? v : 0.f;
                C[(size_t)row * ldc + col] = __float2bfloat16(v);
            }
}

// ---------------------------------------------------------------------------
// fc2: 64x128 tile, fp32 out. 768 balanced blocks.
// ---------------------------------------------------------------------------
__global__ __launch_bounds__(256)
void gemm_bt64(const bf16* __restrict__ A0, int lda0, int K0,
               const bf16* __restrict__ A1, int lda1, int K1,
               const bf16* __restrict__ B0, int ldb0,
               const bf16* __restrict__ B1, int ldb1,
               const float* __restrict__ bias,
               float* __restrict__ Cf, int ldc)
{
    __shared__ bf16 sA[64 * BK];
    __shared__ bf16 sB[128 * BK];

    const int t = threadIdx.x;
    const int w = t >> 6;
    const int l = t & 63;
    const int wn = w;
    const int r = l & 15;
    const int q = l >> 4;
    const int sw = r & 7;
    const int rowA0 = blockIdx.x * 64;
    const int rowB0 = blockIdx.y * 128;

    f32x4 acc[4][2];
#pragma unroll
    for (int i = 0; i < 4; ++i)
#pragma unroll
        for (int j = 0; j < 2; ++j)
            acc[i][j] = (f32x4){0.f, 0.f, 0.f, 0.f};

    const int nK = (K0 + K1) >> 6;
    for (int kt = 0; kt < nK; ++kt) {
        const int k0 = kt << 6;
        const bf16 *Ap, *Bp;
        int la, lb, ks;
        if (k0 < K0) { Ap = A0; la = lda0; Bp = B0; lb = ldb0; ks = k0; }
        else         { Ap = A1; la = lda1; Bp = B1; lb = ldb1; ks = k0 - K0; }

        __syncthreads();
#pragma unroll
        for (int it = 0; it < 2; ++it) {
            const int L   = it * 256 + t;
            const int row = L >> 3;
            const int cb  = (L & 7) ^ (row & 7);
            stage16(Ap + (size_t)(rowA0 + row) * la + ks + cb * 8,
                    sA + (size_t)(it * 256 + (w << 6)) * 8);
        }
#pragma unroll
        for (int it = 0; it < 4; ++it) {
            const int L   = it * 256 + t;
            const int row = L >> 3;
            const int cb  = (L & 7) ^ (row & 7);
            stage16(Bp + (size_t)(rowB0 + row) * lb + ks + cb * 8,
                    sB + (size_t)(it * 256 + (w << 6)) * 8);
        }
        __syncthreads();

#pragma unroll
        for (int kk = 0; kk < 2; ++kk) {
            const int ch = ((kk * 4 + q) ^ sw) * 8;
            bf16x8 aF[4], bF[2];
#pragma unroll
            for (int i = 0; i < 4; ++i)
                aF[i] = *(const bf16x8*)&sA[(i * 16 + r) * BK + ch];
#pragma unroll
            for (int j = 0; j < 2; ++j)
                bF[j] = *(const bf16x8*)&sB[(wn * 32 + j * 16 + r) * BK + ch];
#pragma unroll
            for (int i = 0; i < 4; ++i)
#pragma unroll
                for (int j = 0; j < 2; ++j)
                    acc[i][j] = __builtin_amdgcn_mfma_f32_16x16x32_bf16(
                        aF[i], bF[j], acc[i][j], 0, 0, 0);
        }
    }

#pragma unroll
    for (int i = 0; i < 4; ++i)
#pragma unroll
        for (int j = 0; j < 2; ++j)
#pragma unroll
            for (int rr = 0; rr < 4; ++rr) {
                const int row = rowA0 + i * 16 + q * 4 + rr;
                const int col = rowB0 + wn * 32 + j * 16 + r;
                Cf[(size_t)row * ldc + col] = acc[i][j][rr] + bias[col];
            }
}

// ---------------------------------------------------------------------------
// Fused router + t1 GEMM, 64-row tiles (384 blocks for TLP).
// B = [gate_w1 ; SVH1] contiguous [384,768]. Grid (128, 3), K=768 full.
//   y=0,1 (router): bias+relu+64-row sum -> atomicAdd gsum[16,256].
//   y=2   (t1):     raw fp32 x@SVH1^T -> t1acc (non-atomic).
// ---------------------------------------------------------------------------
__global__ __launch_bounds__(256)
void rt1_kernel(const bf16* __restrict__ A, int lda,
                const bf16* __restrict__ B, int ldb,
                const float* __restrict__ gate_b1,
                float* __restrict__ gsum, float* __restrict__ t1acc)
{
    __shared__ bf16 sA[64 * BK];
    __shared__ bf16 sB[128 * BK];

    const int t = threadIdx.x;
    const int w = t >> 6;
    const int l = t & 63;
    const int wn = w;
    const int r = l & 15;
    const int q = l >> 4;
    const int sw = r & 7;
    const int rowA0 = blockIdx.x * 64;
    const int rowB0 = blockIdx.y * 128;
    const int b = rowA0 >> 9;

    f32x4 acc[4][2];
#pragma unroll
    for (int i = 0; i < 4; ++i)
#pragma unroll
        for (int j = 0; j < 2; ++j)
            acc[i][j] = (f32x4){0.f, 0.f, 0.f, 0.f};

    for (int kt = 0; kt < 12; ++kt) {      // K = 768
        const int ks = kt << 6;

        __syncthreads();
#pragma unroll
        for (int it = 0; it < 2; ++it) {
            const int L   = it * 256 + t;
            const int row = L >> 3;
            const int cb  = (L & 7) ^ (row & 7);
            stage16(A + (size_t)(rowA0 + row) * lda + ks + cb * 8,
                    sA + (size_t)(it * 256 + (w << 6)) * 8);
        }
#pragma unroll
        for (int it = 0; it < 4; ++it) {
            const int L   = it * 256 + t;
            const int row = L >> 3;
            const int cb  = (L & 7) ^ (row & 7);
            stage16(B + (size_t)(rowB0 + row) * ldb + ks + cb * 8,
                    sB + (size_t)(it * 256 + (w << 6)) * 8);
        }
        __syncthreads();

#pragma unroll
        for (int kk = 0; kk < 2; ++kk) {
            const int ch = ((kk * 4 + q) ^ sw) * 8;
            bf16x8 aF[4], bF[2];
#pragma unroll
            for (int i = 0; i < 4; ++i)
                aF[i] = *(const bf16x8*)&sA[(i * 16 + r) * BK + ch];
#pragma unroll
            for (int j = 0; j < 2; ++j)
                bF[j] = *(const bf16x8*)&sB[(wn * 32 + j * 16 + r) * BK + ch];
#pragma unroll
            for (int i = 0; i < 4; ++i)
#pragma unroll
                for (int j = 0; j < 2; ++j)
                    acc[i][j] = __builtin_amdgcn_mfma_f32_16x16x32_bf16(
                        aF[i], bF[j], acc[i][j], 0, 0, 0);
        }
    }

    if (rowB0 < 256) {
#pragma unroll
        for (int j = 0; j < 2; ++j) {
            const int col = rowB0 + wn * 32 + j * 16 + r;
            const float bc = gate_b1[col];
            float s = 0.f;
#pragma unroll
            for (int i = 0; i < 4; ++i)
#pragma unroll
                for (int rr = 0; rr < 4; ++rr) {
                    const float v = acc[i][j][rr] + bc;
                    s += v > 0.f ? v : 0.f;
                }
            s += __shfl_xor(s, 16, 64);
            s += __shfl_xor(s, 32, 64);
            if (q == 0) atomicAdd(&gsum[b * 256 + col], s);
        }
    } else {
#pragma unroll
        for (int i = 0; i < 4; ++i)
#pragma unroll
            for (int j = 0; j < 2; ++j)
#pragma unroll
                for (int rr = 0; rr < 4; ++rr) {
                    const int row = rowA0 + i * 16 + q * 4 + rr;
                    const int col = wn * 32 + j * 16 + r;
                    t1acc[(size_t)row * 128 + col] = acc[i][j][rr];
                }
    }
}

// ---------------------------------------------------------------------------
// t2 split-K: grid (128, 1, 8), 64x128 tiles, 6 K-tiles per z, atomicAdd
// into pre-zeroed t2acc fp32. 1024 blocks = 4/CU for latency hiding.
// ---------------------------------------------------------------------------
__global__ __launch_bounds__(256)
void t2_splitk(const bf16* __restrict__ A, int lda,
               const bf16* __restrict__ B, int ldb,
               float* __restrict__ Cacc)
{
    __shared__ bf16 sA[64 * BK];
    __shared__ bf16 sB[128 * BK];

    const int t = threadIdx.x;
    const int w = t >> 6;
    const int l = t & 63;
    const int wn = w;
    const int r = l & 15;
    const int q = l >> 4;
    const int sw = r & 7;
    const int rowA0 = blockIdx.x * 64;
    const int ksbase = blockIdx.z * 6 * BK;

    f32x4 acc[4][2];
#pragma unroll
    for (int i = 0; i < 4; ++i)
#pragma unroll
        for (int j = 0; j < 2; ++j)
            acc[i][j] = (f32x4){0.f, 0.f, 0.f, 0.f};

    for (int kt = 0; kt < 6; ++kt) {
        const int ks = ksbase + kt * BK;

        __syncthreads();
#pragma unroll
        for (int it = 0; it < 2; ++it) {
            const int L   = it * 256 + t;
            const int row = L >> 3;
            const int cb  = (L & 7) ^ (row & 7);
            stage16(A + (size_t)(rowA0 + row) * lda + ks + cb * 8,
                    sA + (size_t)(it * 256 + (w << 6)) * 8);
        }
#pragma unroll
        for (int it = 0; it < 4; ++it) {
            const int L   = it * 256 + t;
            const int row = L >> 3;
            const int cb  = (L & 7) ^ (row & 7);
            stage16(B + (size_t)row * ldb + ks + cb * 8,
                    sB + (size_t)(it * 256 + (w << 6)) * 8);
        }
        __syncthreads();

#pragma unroll
        for (int kk = 0; kk < 2; ++kk) {
            const int ch = ((kk * 4 + q) ^ sw) * 8;
            bf16x8 aF[4], bF[2];
#pragma unroll
            for (int i = 0; i < 4; ++i)
                aF[i] = *(const bf16x8*)&sA[(i * 16 + r) * BK + ch];
#pragma unroll
            for (int j = 0; j < 2; ++j)
                bF[j] = *(const bf16x8*)&sB[(wn * 32 + j * 16 + r) * BK + ch];
#pragma unroll
            for (int i = 0; i < 4; ++i)
#pragma unroll
                for (int j = 0; j < 2; ++j)
                    acc[i][j] = __builtin_amdgcn_mfma_f32_16x16x32_bf16(
                        aF[i], bF[j], acc[i][j], 0, 0, 0);
        }
    }

#pragma unroll
    for (int i = 0; i < 4; ++i)
#pragma unroll
        for (int j = 0; j < 2; ++j)
#pragma unroll
            for (int rr = 0; rr < 4; ++rr) {
                const int row = rowA0 + i * 16 + q * 4 + rr;
                const int col = wn * 32 + j * 16 + r;
                atomicAdd(&Cacc[(size_t)row * 128 + col], acc[i][j][rr]);
            }
}

// t[i] = bf16(acc[i] * gw[batch(row)][col])   (M x 128)
__global__ void scale_cvt_kernel(const float* __restrict__ acc,
                                 const float* __restrict__ gw,
                                 bf16* __restrict__ outb)
{
    const int i = blockIdx.x * 256 + threadIdx.x;
    const int col = i & 127;
    const int row = i >> 7;
    outb[i] = __float2bfloat16(acc[i] * gw[(row >> 9) * 128 + col]);
}

// ---------------------------------------------------------------------------
// Fused prep: fp32->bf16 casts + coalesced LDS-tile U transposes + merged
// biases + zeroing of gsum and t2acc. One launch.
// ---------------------------------------------------------------------------
__device__ __forceinline__ void cvt_range(const float* src, bf16* dst, int base, int t)
{
    const int i = base * 256 + t;
    const float4 v = ((const float4*)src)[i];
    ((bf16x4*)dst)[i] = (bf16x4){(__bf16)v.x, (__bf16)v.y, (__bf16)v.z, (__bf16)v.w};
}

__device__ __forceinline__ void transpose_tile(const float* U, bf16* UT, int F,
                                               int bx, int by, int t,
                                               float (*sh)[65])
{
    const int f0 = bx * 64, ek0 = by * 64;
#pragma unroll
    for (int i = 0; i < 16; ++i) {
        const int row = i * 4 + (t >> 6);
        const int col = t & 63;
        sh[row][col] = U[(size_t)(ek0 + row) * F + f0 + col];
    }
    __syncthreads();
#pragma unroll
    for (int i = 0; i < 16; ++i) {
        const int row = i * 4 + (t >> 6);
        const int col = t & 63;
        UT[(size_t)(f0 + row) * 128 + ek0 + col] = __float2bfloat16(sh[col][row]);
    }
}

__global__ void prep_all(const float* __restrict__ x,    bf16* __restrict__ xb,
                         const float* __restrict__ W1,   bf16* __restrict__ W1b,
                         const float* __restrict__ W2,   bf16* __restrict__ W2b,
                         const float* __restrict__ gw1,  bf16* __restrict__ gw1b,
                         const float* __restrict__ gw2,  bf16* __restrict__ gw2b,
                         const float* __restrict__ SVH1, bf16* __restrict__ svh1b,
                         const float* __restrict__ SVH2, bf16* __restrict__ svh2b,
                         const float* __restrict__ U1,   bf16* __restrict__ U1T,
                         const float* __restrict__ U2,   bf16* __restrict__ U2T,
                         const float* __restrict__ b1,   const float* __restrict__ TB1,
                         const float* __restrict__ b2,   const float* __restrict__ TB2,
                         float* __restrict__ b1m, float* __restrict__ b2m,
                         float* __restrict__ gsum, float* __restrict__ t2acc)
{
    __shared__ float sh[64][65];
    const int b = blockIdx.x;
    const int t = threadIdx.x;
    if      (b < 6144)  cvt_range(x,   xb,   b,         t);
    else if (b < 8448)  cvt_range(W1,  W1b,  b - 6144,  t);
    else if (b < 10752) cvt_range(W2,  W2b,  b - 8448,  t);
    else if (b < 10944) cvt_range(gw1, gw1b, b - 10752, t);
    else if (b < 10976) cvt_range(gw2, gw2b, b - 10944, t);
    else if (b < 11072) cvt_range(SVH1, svh1b, b - 10976, t);
    else if (b < 11456) cvt_range(SVH2, svh2b, b - 11072, t);
    else if (b < 11552) {          // U1 [128,3072] -> U1T: 48 x 2 tiles
        const int b2 = b - 11456;
        transpose_tile(U1, U1T, 3072, b2 >> 1, b2 & 1, t, sh);
    } else if (b < 11576) {        // U2 [128,768] -> U2T: 12 x 2 tiles
        const int b2 = b - 11552;
        transpose_tile(U2, U2T, 768, b2 >> 1, b2 & 1, t, sh);
    } else if (b < 11591) {        // merged biases
        const int i = (b - 11576) * 256 + t;
        if (i < 3072) {
            float s = 0.f;
            for (int e = 0; e < 8; ++e) s += TB1[e * 3072 + i];
            b1m[i] = b1[i] + 0.2f * s;
        } else if (i < 3840) {
            const int j = i - 3072;
            float s = 0.f;
            for (int e = 0; e < 8; ++e) s += TB2[e * 768 + j];
            b2m[j] = b2[j] + 0.2f * s;
        }
    } else if (b < 11607) {        // zero gsum[4096]
        const int i = (b - 11591) * 256 + t;
        gsum[i] = 0.f;
    } else {                       // zero t2acc: 1M floats as float4
        const int i = (b - 11607) * 256 + t;
        ((float4*)t2acc)[i] = (float4){0.f, 0.f, 0.f, 0.f};
    }
}

// gw[b,c] = gate_b2[c] + (1/512) * sum_j gsum[b,j] * gate_w2[c,j]
__global__ void gw_kernel(const float* __restrict__ gsum, const bf16* __restrict__ gw2b,
                          const float* __restrict__ gate_b2, float* __restrict__ gw)
{
    const int b = blockIdx.x;
    const int c = threadIdx.x;
    float s = 0.f;
    for (int j = 0; j < 256; ++j)
        s += gsum[b * 256 + j] * __bfloat162float(gw2b[c * 256 + j]);
    gw[b * 128 + c] = gate_b2[c] + s * (1.0f / 512.0f);
}

// ---------------------------------------------------------------------------
extern "C" void kernel_launch(void* const* d_in, const int* in_sizes, int n_in,
                              void* d_out, int out_size, void* d_ws, size_t ws_size,
                              hipStream_t stream)
{
    const float* x       = (const float*)d_in[0];
    const float* gate_w1 = (const float*)d_in[1];
    const float* gate_b1 = (const float*)d_in[2];
    const float* gate_w2 = (const float*)d_in[3];
    const float* gate_b2 = (const float*)d_in[4];
    const float* W1      = (const float*)d_in[5];
    const float* b1      = (const float*)d_in[6];
    const float* W2      = (const float*)d_in[7];
    const float* b2      = (const float*)d_in[8];
    const float* U1      = (const float*)d_in[9];
    const float* SVH1    = (const float*)d_in[10];
    const float* U2      = (const float*)d_in[11];
    const float* SVH2    = (const float*)d_in[12];
    const float* TB1     = (const float*)d_in[13];
    const float* TB2     = (const float*)d_in[14];
    float* out = (float*)d_out;                     // [8192, 768] fp32

    char* p = (char*)d_ws;
    auto alloc = [&](size_t bytes) {
        char* q = p;
        p += (bytes + 255) & ~(size_t)255;
        return q;
    };
    bf16* hbuf  = (bf16*)alloc((size_t)8192 * 3072 * 2);
    bf16* xb    = (bf16*)alloc((size_t)8192 * 768 * 2);
    bf16* t1buf = (bf16*)alloc((size_t)8192 * 128 * 2);
    bf16* t2buf = (bf16*)alloc((size_t)8192 * 128 * 2);
    bf16* W1b   = (bf16*)alloc((size_t)3072 * 768 * 2);
    bf16* W2b   = (bf16*)alloc((size_t)768 * 3072 * 2);
    // gw1b and svh1b MUST be contiguous: rt1_kernel treats them as one
    // [384, 768] B matrix. 256*768*2 = 393216 B (multiple of 256 -> no pad).
    bf16* gw1b  = (bf16*)alloc((size_t)256 * 768 * 2);
    bf16* svh1b = (bf16*)alloc((size_t)128 * 768 * 2);
    bf16* gw2b  = (bf16*)alloc((size_t)128 * 256 * 2);
    bf16* svh2b = (bf16*)alloc((size_t)128 * 3072 * 2);
    bf16* U1T   = (bf16*)alloc((size_t)3072 * 128 * 2);
    bf16* U2T   = (bf16*)alloc((size_t)768 * 128 * 2);
    float* gsum = (float*)alloc(16 * 256 * 4);
    float* gw   = (float*)alloc(2048 * 4);
    float* b1m  = (float*)alloc(3072 * 4);
    float* b2m  = (float*)alloc(768 * 4);
    float* t1acc = (float*)alloc((size_t)8192 * 128 * 4);
    float* t2acc = (float*)alloc((size_t)8192 * 128 * 4);

    const dim3 blk(256);

    prep_all<<<12631, blk, 0, stream>>>(x, xb, W1, W1b, W2, W2b,
                                        gate_w1, gw1b, gate_w2, gw2b,
                                        SVH1, svh1b, SVH2, svh2b,
                                        U1, U1T, U2, U2T,
                                        b1, TB1, b2, TB2, b1m, b2m,
                                        gsum, t2acc);

    // fused router + t1raw (64-row tiles, 384 blocks)
    rt1_kernel<<<dim3(128, 3), blk, 0, stream>>>(xb, 768, gw1b, 768,
                                                 gate_b1, gsum, t1acc);
    // gw = gsum/512 @ gate_w2^T + gate_b2              [16, 128]
    gw_kernel<<<16, 128, 0, stream>>>(gsum, gw2b, gate_b2, gw);
    // t1 = t1acc * gw -> bf16
    scale_cvt_kernel<<<4096, blk, 0, stream>>>(t1acc, gw, t1buf);

    // h = relu([x|t1] @ [W1|U1T]^T + b1m)              [8192, 3072]
    gemm_bt<<<dim3(64, 24), blk, 0, stream>>>(xb, 768, 768, t1buf, 128, 128,
                                              W1b, 768, U1T, 128,
                                              b1m, 1, hbuf, 3072);

    // t2acc += h @ SVH2^T  (split-K z=8, 1024 blocks)  [8192, 128]
    t2_splitk<<<dim3(128, 1, 8), blk, 0, stream>>>(hbuf, 3072, svh2b, 3072, t2acc);
    // t2 = t2acc * gw -> bf16
    scale_cvt_kernel<<<4096, blk, 0, stream>>>(t2acc, gw, t2buf);

    // out = [h|t2] @ [W2|U2T]^T + b2m  (fp32 out)      [8192, 768]
    gemm_bt64<<<dim3(128, 6), blk, 0, stream>>>(hbuf, 3072, 3072, t2buf, 128, 128,
                                                W2b, 3072, U2T, 128,
                                                b2m, out, 768);
}